// Round 3
// baseline (171.144 us; speedup 1.0000x reference)
//
#include <hip/hip_runtime.h>

// Problem constants (hardcoded; spatial_shapes = [[4,8]]*4)
//  bs=64, nq=64, E=256, Hn=8, dh=32, L=4, P=16, BEV=2, Pb=32
//  qb=128 collapses to 64. OFF col (h,f,c)=h*256+2f+c; rp level = f&3;
//  image level = f>>5 = wave; attn key = f; output pairs (2q,2q+1) -> pj/pj+32.
//
// ws: [0,1M) Wtb bf16 [2048][256] | [1M,3M) Qb bf16 [4096][256]
//     [3M,5M) Khb bf16 [4096][256]
//
// mega5 (this round): q-SPLIT for occupancy. R1/R2 showed mega's ~92us is
// invariant to barriers/staging -> latency-bound at grid-capped 2 blocks/CU.
// Split each (h,b) into qh={0,1} halves of 32 q-rows: grid 512->1024,
// LDS 79360->35328 (Amb unioned onto dead attLb) -> 4 blocks/CU, 16 waves/CU.
// Also: grid dim3(64,8,2) makes XCD = b%8 (was h) -> per-XCD L2 working set
// ~2.5MB (fits 4MB) instead of thrashing Qb+Khb.

typedef short  s16x8 __attribute__((ext_vector_type(8)));
typedef short  s16x4 __attribute__((ext_vector_type(4)));
typedef float  f32x4 __attribute__((ext_vector_type(4)));

__device__ __forceinline__ unsigned short f2bf(float f) {
    union { float f; unsigned u; } v; v.f = f;
    unsigned r = v.u + 0x7FFFu + ((v.u >> 16) & 1u);   // RNE
    return (unsigned short)(r >> 16);
}
__device__ __forceinline__ float bf2f(unsigned short u) {
    return __uint_as_float(((unsigned)u) << 16);
}

// ---------------------------------------------------------------------------
// prep: [0,512) W transpose f32->bf16 ; [512,1536) query->Qb ;
//       [1536,2560) key_hist->Khb   (unchanged, verified)
// ---------------------------------------------------------------------------
__global__ __launch_bounds__(256) void prep(
    const float* __restrict__ W, const float* __restrict__ query,
    const float* __restrict__ key_hist,
    short* __restrict__ Wtb, short* __restrict__ Qb, short* __restrict__ Khb)
{
    __shared__ float s[32][33];
    const int bx = blockIdx.x, t = threadIdx.x;
    if (bx < 512) {
        const int n0 = (bx & 63) * 32, k0 = (bx >> 6) * 32;
        const int c = t & 31, r0 = t >> 5;
        #pragma unroll
        for (int p = 0; p < 4; ++p) {
            const int r = r0 + p * 8;
            s[r][c] = W[(size_t)(k0 + r) * 2048 + n0 + c];
        }
        __syncthreads();
        #pragma unroll
        for (int p = 0; p < 4; ++p) {
            const int r = r0 + p * 8;
            Wtb[(size_t)(n0 + r) * 256 + k0 + c] = (short)f2bf(s[c][r]);
        }
    } else {
        const int j = bx - 512;
        const bool isK = j >= 1024;
        const float* src = isK ? key_hist : query;
        short* dst = isK ? Khb : Qb;
        const int i4 = ((j & 1023) * 256 + t) * 4;
        const float4 v = *(const float4*)(src + i4);
        s16x4 o;
        o.x = (short)f2bf(v.x); o.y = (short)f2bf(v.y);
        o.z = (short)f2bf(v.z); o.w = (short)f2bf(v.w);
        *(s16x4*)(dst + i4) = o;
    }
}

// ---------------------------------------------------------------------------
// mega5: one block per (b,h,qh). LDS 35328 B -> 4 blocks/CU, 16 waves/CU.
// ---------------------------------------------------------------------------
__global__ __launch_bounds__(256, 4) void mega5(
    const float* __restrict__ query, const float* __restrict__ value_hist,
    const float* __restrict__ refp,
    const short* __restrict__ Qb, const short* __restrict__ Khb,
    const short* __restrict__ Wtb, const float* __restrict__ bias,
    float* __restrict__ out)
{
    const int b = blockIdx.x, h = blockIdx.y, qh = blockIdx.z;
    const int t = threadIdx.x, lane = t & 63, wave = t >> 6;
    const int quad = lane >> 4, col = lane & 15;
    const int qbase = 32 * qh;

    __shared__ __align__(16) short VTl[32 * 136];   // V^T [d][p], 8704 B
    __shared__ __align__(16) short attLb[32 * 136]; // probs bf16; Amb after B2
    __shared__ __align__(16) float rpsL[256];       // block's 32 refp rows
    __shared__ __align__(16) float Am[32 * 132];    // scatter acc f32, 16896 B

    // ============ Phase A: everything before the first barrier ============
    // A1: stage VTl (values = [query rows | value_hist rows], h-slice, ^T)
    //     qh-independent (all 128 positions needed by AV).
    {
        const int p = t >> 1, hf = (t & 1) * 16;
        const float* src = ((p < 64) ? query : value_hist) +
                           (size_t)(b * 64 + (p & 63)) * 256 + h * 32 + hf;
        #pragma unroll
        for (int u = 0; u < 4; ++u) {
            const float4 v = *(const float4*)(src + 4 * u);
            VTl[(hf + 4 * u + 0) * 136 + p] = (short)f2bf(v.x);
            VTl[(hf + 4 * u + 1) * 136 + p] = (short)f2bf(v.y);
            VTl[(hf + 4 * u + 2) * 136 + p] = (short)f2bf(v.z);
            VTl[(hf + 4 * u + 3) * 136 + p] = (short)f2bf(v.w);
        }
    }
    // A2: refp rows for this q-half + zero Am (32*132 = 4224 floats)
    rpsL[t & 255] = refp[(size_t)b * 512 + qbase * 8 + (t & 255)];
    #pragma unroll
    for (int u = 0; u < 16; ++u) Am[t + 256 * u] = 0.f;
    if (t < 128) Am[4096 + t] = 0.f;

    // A3: offsets GEMM, N-split: wave owns n' in [64*wave, +64).
    //     M=32 (this q-half): acc[mi][nj], q = qbase+16mi+4quad+reg,
    //     n' = 64*wave + 16nj + col. A/B frags direct from L2.
    f32x4 acc[2][4] = {};
    #pragma unroll
    for (int kq = 0; kq < 4; ++kq) {
        s16x8 afp[2][2], bfp[4][2];
        #pragma unroll
        for (int mi = 0; mi < 2; ++mi)
            #pragma unroll
            for (int ks = 0; ks < 2; ++ks)
                afp[mi][ks] = *(const s16x8*)(Qb +
                    ((size_t)b * 64 + qbase + 16 * mi + col) * 256
                    + kq * 64 + ks * 32 + quad * 8);
        #pragma unroll
        for (int nj = 0; nj < 4; ++nj)
            #pragma unroll
            for (int ks = 0; ks < 2; ++ks)
                bfp[nj][ks] = *(const s16x8*)(Wtb +
                    ((size_t)(h * 256 + wave * 64 + 16 * nj + col)) * 256
                    + kq * 64 + ks * 32 + quad * 8);
        #pragma unroll
        for (int ks = 0; ks < 2; ++ks)
            #pragma unroll
            for (int mi = 0; mi < 2; ++mi)
                #pragma unroll
                for (int nj = 0; nj < 4; ++nj)
                    acc[mi][nj] = __builtin_amdgcn_mfma_f32_16x16x32_bf16(
                        afp[mi][ks], bfp[nj][ks], acc[mi][nj], 0, 0, 0);
    }

    // A4: logits + softmax on waves 0,1 (strip s=wave: 16 q-rows each).
    //     Keys are ALL 128 ([query 64 | key_hist 64]) regardless of qh.
    if (wave < 2) {
        const int s = wave;
        const s16x8 aq = *(const s16x8*)(Qb +
            ((size_t)b * 64 + qbase + 16 * s + col) * 256 + h * 32 + quad * 8);
        f32x4 lacc[8];
        #pragma unroll
        for (int t8 = 0; t8 < 8; ++t8) {
            const short* src = (t8 < 4)
                ? (Qb  + ((size_t)b * 64 + 16 * t8 + col) * 256)
                : (Khb + ((size_t)b * 64 + 16 * (t8 - 4) + col) * 256);
            const s16x8 bk = *(const s16x8*)(src + h * 32 + quad * 8);
            const f32x4 z = {0.f, 0.f, 0.f, 0.f};
            lacc[t8] = __builtin_amdgcn_mfma_f32_16x16x32_bf16(aq, bk, z, 0, 0, 0);
        }
        #pragma unroll
        for (int r = 0; r < 4; ++r) {
            float m = lacc[0][r];
            #pragma unroll
            for (int t8 = 1; t8 < 8; ++t8) m = fmaxf(m, lacc[t8][r]);
            #pragma unroll
            for (int sh = 1; sh < 16; sh <<= 1) m = fmaxf(m, __shfl_xor(m, sh, 64));
            float e[8], ssum = 0.f;
            #pragma unroll
            for (int t8 = 0; t8 < 8; ++t8) {
                e[t8] = __expf(lacc[t8][r] - m); ssum += e[t8];
            }
            #pragma unroll
            for (int sh = 1; sh < 16; sh <<= 1) ssum += __shfl_xor(ssum, sh, 64);
            const float inv = 1.0f / ssum;
            const int ql = 16 * s + 4 * quad + r;        // local q row 0..31
            #pragma unroll
            for (int t8 = 0; t8 < 8; ++t8)
                attLb[ql * 136 + 16 * t8 + col] = (short)f2bf(e[t8] * inv);
        }
    }

    // A5: bias prefetch for this wave's n' columns
    float bjv[4];
    #pragma unroll
    for (int nj = 0; nj < 4; ++nj)
        bjv[nj] = bias[h * 256 + wave * 64 + 16 * nj + col];

    __syncthreads();   // B1: VTl, rpsL, Am-zero, attLb visible

    // ============ Phase B: bilinear scatter (wave w -> level w cols) =======
    {
        const int i   = col >> 1;          // f-sub 0..7 ; rp level = i&3
        const int par = col & 1;           // 0: x-coords, 1: y-coords
        const int base = 32 * wave;        // image level = f>>5 = wave
        #pragma unroll
        for (int nj = 0; nj < 4; ++nj) {
            const int f = 32 * wave + 8 * nj + i;
            #pragma unroll
            for (int mi = 0; mi < 2; ++mi) {
                float v[4], p[4];
                #pragma unroll
                for (int r = 0; r < 4; ++r) v[r] = acc[mi][nj][r] + bjv[nj];
                #pragma unroll
                for (int r = 0; r < 4; ++r) p[r] = __shfl_xor(v[r], 1, 64);
                #pragma unroll
                for (int rs = 0; rs < 2; ++rs) {
                    const int r = par * 2 + rs;
                    const float ox = par ? p[r] : v[r];
                    const float oy = par ? v[r] : p[r];
                    const int ql = 16 * mi + 4 * quad + r;   // local 0..31
                    const float2 rp = *(const float2*)&rpsL[ql * 8 + (i & 3) * 2];
                    const float a = bf2f((unsigned short)attLb[ql * 136 + f]);
                    const float gx = 8.f * (rp.x + ox * 0.125f) - 0.5f;
                    const float gy = 4.f * (rp.y + oy * 0.25f) - 0.5f;
                    const float x0f = floorf(gx), y0f = floorf(gy);
                    const float wx = gx - x0f, wy = gy - y0f;
                    const int x0 = (int)x0f, y0 = (int)y0f;
                    float* rowW = &Am[ql * 132 + base];
                    const bool xv0 = (x0 >= 0) && (x0 < 8);
                    const bool xv1 = (x0 >= -1) && (x0 < 7);
                    const bool yv0 = (y0 >= 0) && (y0 < 4);
                    const bool yv1 = (y0 >= -1) && (y0 < 3);
                    if (xv0 && yv0) unsafeAtomicAdd(&rowW[y0 * 8 + x0],           a * (1.f - wx) * (1.f - wy));
                    if (xv1 && yv0) unsafeAtomicAdd(&rowW[y0 * 8 + x0 + 1],       a * wx * (1.f - wy));
                    if (xv0 && yv1) unsafeAtomicAdd(&rowW[(y0 + 1) * 8 + x0],     a * (1.f - wx) * wy);
                    if (xv1 && yv1) unsafeAtomicAdd(&rowW[(y0 + 1) * 8 + x0 + 1], a * wx * wy);
                }
            }
        }
    }
    __syncthreads();   // B2: scatter complete; attLb dead -> becomes Amb

    // ============ Phase C: Am(f32) -> Amb(bf16), Amb aliases attLb =========
    {
        short* Amb = attLb;
        const int cq = t >> 3, cc = (t & 7) * 16;
        #pragma unroll
        for (int u = 0; u < 2; ++u) {
            const f32x4 v0 = *(const f32x4*)&Am[cq * 132 + cc + 8 * u];
            const f32x4 v1 = *(const f32x4*)&Am[cq * 132 + cc + 8 * u + 4];
            s16x8 o;
            o[0] = (short)f2bf(v0[0]); o[1] = (short)f2bf(v0[1]);
            o[2] = (short)f2bf(v0[2]); o[3] = (short)f2bf(v0[3]);
            o[4] = (short)f2bf(v1[0]); o[5] = (short)f2bf(v1[1]);
            o[6] = (short)f2bf(v1[2]); o[7] = (short)f2bf(v1[3]);
            *(s16x8*)&Amb[cq * 136 + cc + u * 8] = o;
        }
    }
    __syncthreads();   // B3: Amb ready

    // ============ Phase D: AV MFMA, wave -> (q-strip s, d-half n2) =========
    {
        const short* Amb = attLb;
        const int s = wave & 1, n2 = wave >> 1;
        f32x4 oacc = {0.f, 0.f, 0.f, 0.f};
        #pragma unroll
        for (int ks = 0; ks < 4; ++ks) {
            const s16x8 af = *(const s16x8*)&Amb[(16 * s + col) * 136
                                                 + ks * 32 + quad * 8];
            const s16x8 bv = *(const s16x8*)&VTl[(n2 * 16 + col) * 136
                                                 + ks * 32 + quad * 8];
            oacc = __builtin_amdgcn_mfma_f32_16x16x32_bf16(af, bv, oacc, 0, 0, 0);
        }
        const int d = h * 32 + n2 * 16 + col;
        #pragma unroll
        for (int pr = 0; pr < 2; ++pr) {
            const float avg = 0.5f * (oacc[2 * pr] + oacc[2 * pr + 1]);
            const int pj = qh * 16 + s * 8 + quad * 2 + pr;
            const size_t re = ((size_t)b * 64 + pj) * 256 + d;
            const size_t ro = ((size_t)b * 64 + pj + 32) * 256 + d;
            out[re] = query[re] + avg;
            out[ro] = query[ro] + avg;
        }
    }
}

extern "C" void kernel_launch(void* const* d_in, const int* in_sizes, int n_in,
                              void* d_out, int out_size, void* d_ws, size_t ws_size,
                              hipStream_t stream) {
    (void)in_sizes; (void)n_in; (void)out_size; (void)ws_size;
    const float* query      = (const float*)d_in[0];
    const float* key_hist   = (const float*)d_in[1];
    const float* value_hist = (const float*)d_in[2];
    const float* refp       = (const float*)d_in[3];
    const float* W_off      = (const float*)d_in[5];
    const float* b_off      = (const float*)d_in[6];

    char* ws = (char*)d_ws;
    short* Wtb = (short*)(ws);                 // 1 MB
    short* Qb  = (short*)(ws + (1u << 20));    // 2 MB
    short* Khb = (short*)(ws + (3u << 20));    // 2 MB
    float* out = (float*)d_out;

    prep<<<2560, 256, 0, stream>>>(W_off, query, key_hist, Wtb, Qb, Khb);
    // grid (b, h, qh): linear id = b + 64h + 512qh -> XCD = b%8
    mega5<<<dim3(64, 8, 2), 256, 0, stream>>>(query, value_hist, refp,
                                              Qb, Khb, Wtb, b_off, out);
}

// Round 4
// 169.822 us; speedup vs baseline: 1.0078x; 1.0078x over previous
//
#include <hip/hip_runtime.h>

// Problem constants (hardcoded; spatial_shapes = [[4,8]]*4)
//  bs=64, nq=64, E=256, Hn=8, dh=32, L=4, P=16, BEV=2, Pb=32
//  qb=128 collapses to 64. OFF col (h,f,c)=h*256+2f+c; rp level = f&3;
//  image level = f>>5 = wave; attn key = f; output pairs (2q,2q+1) -> pj/pj+32.
//
// mega6 (this round): SINGLE FUSED KERNEL, no prep, no workspace.
// R0-R3 showed: mega ~92-99us invariant to barriers/staging/occupancy, while
// a fixed ~71us (prep + 2nd launch + serialization) never moved. Kill it.
//  * GEMM B-frags gathered DIRECTLY from W f32 (column reads: each dword load
//    is 64 consecutive n' across lanes -> fully coalesced) + inline RNE cvt.
//  * A-frags / logit key-frags: row-major 8-float runs from query/key_hist.
//  * Values staging already read f32 sources -> unchanged.
// Numerics identical to mega4 (same RNE bf16, same MFMA order).
// Structure verbatim mega4: N-split GEMM, 3 barriers, LDS 79360 -> 2 blk/CU
// (grid 512 = 2/CU is the cap anyway). Grid dim3(64,8): XCD = b%8.

typedef short  s16x8 __attribute__((ext_vector_type(8)));
typedef float  f32x4 __attribute__((ext_vector_type(4)));

__device__ __forceinline__ unsigned short f2bf(float f) {
    union { float f; unsigned u; } v; v.f = f;
    unsigned r = v.u + 0x7FFFu + ((v.u >> 16) & 1u);   // RNE
    return (unsigned short)(r >> 16);
}
__device__ __forceinline__ float bf2f(unsigned short u) {
    return __uint_as_float(((unsigned)u) << 16);
}
// 8 consecutive f32 -> bf16x8 (row-major run)
__device__ __forceinline__ s16x8 ld8bf(const float* __restrict__ p) {
    const float4 v0 = *(const float4*)p;
    const float4 v1 = *(const float4*)(p + 4);
    s16x8 o;
    o[0] = (short)f2bf(v0.x); o[1] = (short)f2bf(v0.y);
    o[2] = (short)f2bf(v0.z); o[3] = (short)f2bf(v0.w);
    o[4] = (short)f2bf(v1.x); o[5] = (short)f2bf(v1.y);
    o[6] = (short)f2bf(v1.z); o[7] = (short)f2bf(v1.w);
    return o;
}
// W column gather: 8 consecutive k (rows of W), fixed n. Coalesced across
// lanes (lane index varies n by +1).
__device__ __forceinline__ s16x8 ldcol8bf(const float* __restrict__ W,
                                          int k, int n) {
    s16x8 o;
    #pragma unroll
    for (int j = 0; j < 8; ++j)
        o[j] = (short)f2bf(W[(size_t)(k + j) * 2048 + n]);
    return o;
}

// ---------------------------------------------------------------------------
// mega6: one block per (b,h). LDS 79360 B -> 2 blocks/CU. 3 barriers.
// ---------------------------------------------------------------------------
__global__ __launch_bounds__(256, 2) void mega6(
    const float* __restrict__ query, const float* __restrict__ key_hist,
    const float* __restrict__ value_hist, const float* __restrict__ refp,
    const float* __restrict__ W, const float* __restrict__ bias,
    float* __restrict__ out)
{
    const int b = blockIdx.x, h = blockIdx.y;
    const int t = threadIdx.x, lane = t & 63, wave = t >> 6;
    const int quad = lane >> 4, col = lane & 15;
    const int wq = wave * 16;

    __shared__ __align__(16) short VTl[32 * 136];   // V^T [d][p], 8704 B
    __shared__ __align__(16) short attLb[64 * 136]; // att probs bf16, 17408 B
    __shared__ __align__(16) float rpsL[512];       // refp rows, 2048 B
    __shared__ __align__(16) float Am[64 * 132];    // scatter acc f32, 33792 B
    __shared__ __align__(16) short Amb[64 * 136];   // scatter acc bf16, 17408 B

    // ============ Phase A: everything before the first barrier ============
    // A1: stage VTl (values = [query rows | value_hist rows], h-slice, ^T)
    {
        const int p = t >> 1, hf = (t & 1) * 16;
        const float* src = ((p < 64) ? query : value_hist) +
                           (size_t)(b * 64 + (p & 63)) * 256 + h * 32 + hf;
        #pragma unroll
        for (int u = 0; u < 4; ++u) {
            const float4 v = *(const float4*)(src + 4 * u);
            VTl[(hf + 4 * u + 0) * 136 + p] = (short)f2bf(v.x);
            VTl[(hf + 4 * u + 1) * 136 + p] = (short)f2bf(v.y);
            VTl[(hf + 4 * u + 2) * 136 + p] = (short)f2bf(v.z);
            VTl[(hf + 4 * u + 3) * 136 + p] = (short)f2bf(v.w);
        }
    }
    // A2: refp rows + zero Am
    rpsL[t]       = refp[(size_t)b * 512 + t];
    rpsL[t + 256] = refp[(size_t)b * 512 + t + 256];
    #pragma unroll
    for (int u = 0; u < 33; ++u) Am[t + 256 * u] = 0.f;

    // A3: offsets GEMM, N-split: wave owns n' in [64*wave, +64).
    //     acc[mi][nj]; q = 16mi+4quad+reg, n' = 64*wave + 16nj + col.
    //     A-frags: query rows f32 -> bf16. B-frags: W column gather -> bf16.
    f32x4 acc[4][4] = {};
    #pragma unroll
    for (int kq = 0; kq < 4; ++kq) {
        s16x8 afp[4][2], bfp[4][2];
        #pragma unroll
        for (int mi = 0; mi < 4; ++mi)
            #pragma unroll
            for (int ks = 0; ks < 2; ++ks)
                afp[mi][ks] = ld8bf(query +
                    ((size_t)b * 64 + 16 * mi + col) * 256
                    + kq * 64 + ks * 32 + quad * 8);
        #pragma unroll
        for (int nj = 0; nj < 4; ++nj)
            #pragma unroll
            for (int ks = 0; ks < 2; ++ks)
                bfp[nj][ks] = ldcol8bf(W,
                    kq * 64 + ks * 32 + quad * 8,
                    h * 256 + wave * 64 + 16 * nj + col);
        #pragma unroll
        for (int ks = 0; ks < 2; ++ks)
            #pragma unroll
            for (int mi = 0; mi < 4; ++mi)
                #pragma unroll
                for (int nj = 0; nj < 4; ++nj)
                    acc[mi][nj] = __builtin_amdgcn_mfma_f32_16x16x32_bf16(
                        afp[mi][ks], bfp[nj][ks], acc[mi][nj], 0, 0, 0);
    }

    // A4: logits + softmax -> attLb (wave's q-strip rows).
    //     Keys = [query 64 | key_hist 64] rows, h-slice, f32 -> bf16.
    {
        const s16x8 aq = ld8bf(query +
            ((size_t)b * 64 + wq + col) * 256 + h * 32 + quad * 8);
        f32x4 lacc[8];
        #pragma unroll
        for (int t8 = 0; t8 < 8; ++t8) {
            const float* src = (t8 < 4)
                ? (query    + ((size_t)b * 64 + 16 * t8 + col) * 256)
                : (key_hist + ((size_t)b * 64 + 16 * (t8 - 4) + col) * 256);
            const s16x8 bk = ld8bf(src + h * 32 + quad * 8);
            const f32x4 z = {0.f, 0.f, 0.f, 0.f};
            lacc[t8] = __builtin_amdgcn_mfma_f32_16x16x32_bf16(aq, bk, z, 0, 0, 0);
        }
        #pragma unroll
        for (int r = 0; r < 4; ++r) {
            float m = lacc[0][r];
            #pragma unroll
            for (int t8 = 1; t8 < 8; ++t8) m = fmaxf(m, lacc[t8][r]);
            #pragma unroll
            for (int s = 1; s < 16; s <<= 1) m = fmaxf(m, __shfl_xor(m, s, 64));
            float e[8], ssum = 0.f;
            #pragma unroll
            for (int t8 = 0; t8 < 8; ++t8) {
                e[t8] = __expf(lacc[t8][r] - m); ssum += e[t8];
            }
            #pragma unroll
            for (int s = 1; s < 16; s <<= 1) ssum += __shfl_xor(ssum, s, 64);
            const float inv = 1.0f / ssum;
            const int q = wq + 4 * quad + r;
            #pragma unroll
            for (int t8 = 0; t8 < 8; ++t8)
                attLb[q * 136 + 16 * t8 + col] = (short)f2bf(e[t8] * inv);
        }
    }

    // A5: bias prefetch for this wave's n' columns
    float bjv[4];
    #pragma unroll
    for (int nj = 0; nj < 4; ++nj)
        bjv[nj] = bias[h * 256 + wave * 64 + 16 * nj + col];

    __syncthreads();   // B1: VTl, rpsL, Am-zero, attLb all visible

    // ============ Phase B: bilinear scatter (wave w -> level w cols) =======
    {
        const int i   = col >> 1;          // f-sub 0..7 ; rp level = i&3
        const int par = col & 1;           // 0: x-coords, 1: y-coords
        const int base = 32 * wave;        // image level = f>>5 = wave
        #pragma unroll
        for (int nj = 0; nj < 4; ++nj) {
            const int f = 32 * wave + 8 * nj + i;
            #pragma unroll
            for (int mi = 0; mi < 4; ++mi) {
                float v[4], p[4];
                #pragma unroll
                for (int r = 0; r < 4; ++r) v[r] = acc[mi][nj][r] + bjv[nj];
                #pragma unroll
                for (int r = 0; r < 4; ++r) p[r] = __shfl_xor(v[r], 1, 64);
                #pragma unroll
                for (int rs = 0; rs < 2; ++rs) {
                    const int r = par * 2 + rs;
                    const float ox = par ? p[r] : v[r];
                    const float oy = par ? v[r] : p[r];
                    const int q = 16 * mi + 4 * quad + r;
                    const float2 rp = *(const float2*)&rpsL[q * 8 + (i & 3) * 2];
                    const float a = bf2f((unsigned short)attLb[q * 136 + f]);
                    const float gx = 8.f * (rp.x + ox * 0.125f) - 0.5f;
                    const float gy = 4.f * (rp.y + oy * 0.25f) - 0.5f;
                    const float x0f = floorf(gx), y0f = floorf(gy);
                    const float wx = gx - x0f, wy = gy - y0f;
                    const int x0 = (int)x0f, y0 = (int)y0f;
                    float* rowW = &Am[q * 132 + base];
                    const bool xv0 = (x0 >= 0) && (x0 < 8);
                    const bool xv1 = (x0 >= -1) && (x0 < 7);
                    const bool yv0 = (y0 >= 0) && (y0 < 4);
                    const bool yv1 = (y0 >= -1) && (y0 < 3);
                    if (xv0 && yv0) unsafeAtomicAdd(&rowW[y0 * 8 + x0],           a * (1.f - wx) * (1.f - wy));
                    if (xv1 && yv0) unsafeAtomicAdd(&rowW[y0 * 8 + x0 + 1],       a * wx * (1.f - wy));
                    if (xv0 && yv1) unsafeAtomicAdd(&rowW[(y0 + 1) * 8 + x0],     a * (1.f - wx) * wy);
                    if (xv1 && yv1) unsafeAtomicAdd(&rowW[(y0 + 1) * 8 + x0 + 1], a * wx * wy);
                }
            }
        }
    }
    __syncthreads();   // B2: scatter complete

    // ============ Phase C: Am(f32) -> Amb(bf16) ============================
    {
        const int cq = t >> 2, cc = (t & 3) * 32;
        #pragma unroll
        for (int u = 0; u < 4; ++u) {
            const f32x4 v0 = *(const f32x4*)&Am[cq * 132 + cc + 8 * u];
            const f32x4 v1 = *(const f32x4*)&Am[cq * 132 + cc + 8 * u + 4];
            s16x8 o;
            o[0] = (short)f2bf(v0[0]); o[1] = (short)f2bf(v0[1]);
            o[2] = (short)f2bf(v0[2]); o[3] = (short)f2bf(v0[3]);
            o[4] = (short)f2bf(v1[0]); o[5] = (short)f2bf(v1[1]);
            o[6] = (short)f2bf(v1[2]); o[7] = (short)f2bf(v1[3]);
            *(s16x8*)&Amb[cq * 136 + cc + u * 8] = o;
        }
    }
    __syncthreads();   // B3: Amb ready

    // ============ Phase D: AV MFMA + pair-mean + residual ==================
    {
        f32x4 oacc[2] = {};
        #pragma unroll
        for (int ks = 0; ks < 4; ++ks) {
            const s16x8 af = *(const s16x8*)&Amb[(wq + col) * 136 + ks * 32 + quad * 8];
            #pragma unroll
            for (int n2 = 0; n2 < 2; ++n2) {
                const s16x8 bv = *(const s16x8*)&VTl[(n2 * 16 + col) * 136
                                                     + ks * 32 + quad * 8];
                oacc[n2] = __builtin_amdgcn_mfma_f32_16x16x32_bf16(af, bv, oacc[n2], 0, 0, 0);
            }
        }
        #pragma unroll
        for (int n2 = 0; n2 < 2; ++n2) {
            const int d = h * 32 + n2 * 16 + col;
            #pragma unroll
            for (int pr = 0; pr < 2; ++pr) {
                const float avg = 0.5f * (oacc[n2][2 * pr] + oacc[n2][2 * pr + 1]);
                const int pj = wave * 8 + quad * 2 + pr;
                const size_t re = ((size_t)b * 64 + pj) * 256 + d;
                const size_t ro = ((size_t)b * 64 + pj + 32) * 256 + d;
                out[re] = query[re] + avg;
                out[ro] = query[ro] + avg;
            }
        }
    }
}

extern "C" void kernel_launch(void* const* d_in, const int* in_sizes, int n_in,
                              void* d_out, int out_size, void* d_ws, size_t ws_size,
                              hipStream_t stream) {
    (void)in_sizes; (void)n_in; (void)out_size; (void)d_ws; (void)ws_size;
    const float* query      = (const float*)d_in[0];
    const float* key_hist   = (const float*)d_in[1];
    const float* value_hist = (const float*)d_in[2];
    const float* refp       = (const float*)d_in[3];
    const float* W_off      = (const float*)d_in[5];
    const float* b_off      = (const float*)d_in[6];
    float* out = (float*)d_out;

    // grid (b, h): linear id = b + 64h -> XCD = b%8
    mega6<<<dim3(64, 8), 256, 0, stream>>>(query, key_hist, value_hist, refp,
                                           W_off, b_off, out);
}